// Round 2
// baseline (788.297 us; speedup 1.0000x reference)
//
#include <hip/hip_runtime.h>
#include <cmath>

#define NROWS 16384   // B*L = 512*32
#define V 2048
#define VM1 2047      // V-1

__global__ __launch_bounds__(256) void sc_kernel(
    const float* __restrict__ messages,
    const float* __restrict__ logits,
    const float* __restrict__ noise,
    float* __restrict__ out,
    float log_keep, float log_rep_c)
{
    const int row = blockIdx.x;
    const int tid = threadIdx.x;
    const long long N = (long long)NROWS * V;
    const long long mbase = (long long)row * V;
    const float* mrow = messages + mbase;
    const float* lrow = logits + mbase;
    const float* nrow = noise + (long long)row * VM1;

    const int c0 = tid * 8;

    // ---- load message row slice (aligned float4 x2) ----
    float4 m0 = reinterpret_cast<const float4*>(mrow)[tid * 2];
    float4 m1 = reinterpret_cast<const float4*>(mrow)[tid * 2 + 1];
    float m[8] = {m0.x, m0.y, m0.z, m0.w, m1.x, m1.y, m1.z, m1.w};

    // ---- t = masked targets over columns 0..V-2 of ORIGINAL m ----
    float t[8];
    float lsum = 0.0f;
#pragma unroll
    for (int j = 0; j < 8; ++j) {
        int c = c0 + j;
        float tv = 0.0f;
        if (c < VM1) {                 // noise row has V-1 entries; t[2047] doesn't exist
            float u = nrow[c];         // scalar dword load (row stride 2047 -> unaligned for vec)
            tv = (u < 0.1f) ? m[j] : 0.0f;
        }
        t[j] = tv;
        lsum += tv;
    }

    // ---- block reduce row_sum (wave shfl + 4-slot LDS) ----
    float s = lsum;
#pragma unroll
    for (int off = 32; off > 0; off >>= 1) s += __shfl_down(s, off);
    __shared__ float wsum[4];
    __shared__ float edge[256];        // t[7] of each thread, for cross-thread t[c-1]
    edge[tid] = t[7];
    if ((tid & 63) == 0) wsum[tid >> 6] = s;
    __syncthreads();
    float rs = wsum[0] + wsum[1] + wsum[2] + wsum[3];

    const float inv_k = 1.0f / 2046.0f;          // 1/(V-2)
    const float add_c = rs * inv_k;
    const float coef  = 1.0f + inv_k;

    float tprev = (tid == 0) ? 0.0f : edge[tid - 1];
    float o[8];
    // column c = c0 + j ; m_noisy[0] = m[0]; else m[c] + rs/K - t[c-1]*(1+1/K)
    o[0] = (tid == 0) ? m[0] : (m[0] + add_c - tprev * coef);
#pragma unroll
    for (int j = 1; j < 8; ++j) o[j] = m[j] + add_c - t[j - 1] * coef;

    float* out_m = out + mbase;                        // output 0: m_noisy
    reinterpret_cast<float4*>(out_m)[tid * 2]     = make_float4(o[0], o[1], o[2], o[3]);
    reinterpret_cast<float4*>(out_m)[tid * 2 + 1] = make_float4(o[4], o[5], o[6], o[7]);

    float* out_mc = out + 2 * N + mbase;               // output 2: messages copy
    reinterpret_cast<float4*>(out_mc)[tid * 2]     = m0;
    reinterpret_cast<float4*>(out_mc)[tid * 2 + 1] = m1;

    // ---- logits branch ----
    float4 l0 = reinterpret_cast<const float4*>(lrow)[tid * 2];
    float4 l1 = reinterpret_cast<const float4*>(lrow)[tid * 2 + 1];
    float l[8] = {l0.x, l0.y, l0.z, l0.w, l1.x, l1.y, l1.z, l1.w};

    float e0 = expf(lrow[0]);          // broadcast read of row's EOS log-prob

    float ol[8];
#pragma unroll
    for (int j = 0; j < 8; ++j) {
        int c = c0 + j;
        if (c == 0) { ol[j] = l[j]; continue; }        // EOS column passthrough
        float a  = l[j] + log_keep;
        float pt = 1.0f - expf(l[j]) - e0;
        pt = fminf(fmaxf(pt, 0.0f), 1.0f);             // clip(.,0,1)
        float b  = logf(pt) + log_rep_c;               // logf(0) = -inf
        float mx = fmaxf(a, b);
        float mn = fminf(a, b);
        float r;
        if (mn == -INFINITY) r = mx;                   // logaddexp(x,-inf)=x; avoids inf-inf NaN
        else r = mx + log1pf(expf(mn - mx));
        ol[j] = r;
    }

    float* out_l = out + N + mbase;                    // output 1: logits_noisy
    reinterpret_cast<float4*>(out_l)[tid * 2]     = make_float4(ol[0], ol[1], ol[2], ol[3]);
    reinterpret_cast<float4*>(out_l)[tid * 2 + 1] = make_float4(ol[4], ol[5], ol[6], ol[7]);

    float* out_lc = out + 3 * N + mbase;               // output 3: logits copy
    reinterpret_cast<float4*>(out_lc)[tid * 2]     = l0;
    reinterpret_cast<float4*>(out_lc)[tid * 2 + 1] = l1;
}

extern "C" void kernel_launch(void* const* d_in, const int* in_sizes, int n_in,
                              void* d_out, int out_size, void* d_ws, size_t ws_size,
                              hipStream_t stream) {
    const float* messages = (const float*)d_in[0];
    const float* logits   = (const float*)d_in[1];
    const float* noise    = (const float*)d_in[2];
    float* out = (float*)d_out;

    // match reference: float(np.log(...)) computed in double, cast to f32
    float log_keep  = (float)log(1.0 - 0.1);
    float log_rep_c = (float)log(0.1 / 2046.0);

    sc_kernel<<<NROWS, 256, 0, stream>>>(messages, logits, noise, out, log_keep, log_rep_c);
}